// Round 1
// baseline (649.961 us; speedup 1.0000x reference)
//
#include <hip/hip_runtime.h>
#include <hip/hip_bf16.h>
#include <stdint.h>

// HS-MSA: x->QKV proj (bf16 MFMA GEMM), windowed attn (branch1: 64x64 per
// window, branch2: 256x256 across windows), out proj + bias + unwindow.
//
// ws layout (bytes):
//   [0,            393216)   WqkvT bf16 [768][256]  (row c = output channel, k-contig)
//   [393216,       524288)   WoT   bf16 [256][256]
//   [524288,    201850880)   QKV   f32  [65536][768] (windowed row order; c: 0-255 Q, 256-511 K, 512-767 V)
//   [201850880, 235405312)   attnO bf16 [65536][256]
// total ~224.5 MB

typedef float f32x4 __attribute__((ext_vector_type(4)));
typedef __bf16 bf16_t;
typedef __bf16 bf16x8 __attribute__((ext_vector_type(8)));
typedef __bf16 bf16x4 __attribute__((ext_vector_type(4)));

#define SCALE_F 0.17677669529663687f

// windowed row gr = ((b*256 + n)*64 + m)  ->  flat token index in x/out
__device__ __forceinline__ int token_of_row(int gr) {
  int b = gr >> 14, n = (gr >> 6) & 255, m = gr & 63;
  int h = ((n >> 4) << 3) + (m >> 3);
  int w = ((n & 15) << 3) + (m & 7);
  return ((b << 7) + h) * 128 + w;
}

// ---------------- weight prep: transpose + bf16 ----------------
__global__ __launch_bounds__(256) void prep_w_k(
    const float* __restrict__ Wq, const float* __restrict__ Wkv,
    const float* __restrict__ Wo, bf16_t* __restrict__ WqkvT,
    bf16_t* __restrict__ WoT) {
  int tid = blockIdx.x * 256 + threadIdx.x;
  if (tid < 196608) {                 // 256 * 768, coalesced read over c
    int k = tid / 768, c = tid % 768;
    // c<256: Wq col c ; 256<=c<512: K = Wkv col c-256 ; 512<=c<768: V = Wkv col c-256
    float v = (c < 256) ? Wq[k * 256 + c] : Wkv[k * 512 + (c - 256)];
    WqkvT[c * 256 + k] = (bf16_t)v;
  } else {
    int t = tid - 196608;             // 256 * 256
    int k = t / 256, c = t % 256;
    WoT[c * 256 + k] = (bf16_t)Wo[k * 256 + c];
  }
}

// ---------------- GEMM1: QKV = x @ [Wq|Wk|Wv], window-permuted rows ----------------
__global__ __launch_bounds__(256) void gemm_qkv_k(
    const float* __restrict__ x, const bf16_t* __restrict__ Wt,
    float* __restrict__ QKV) {
  __shared__ bf16_t As[128 * 32];   // [row][k], 64B row stride
  __shared__ bf16_t Bs[128 * 32];   // [col][k]
  const int tid = threadIdx.x;
  const int row0 = blockIdx.x * 128;
  const int col0 = blockIdx.y * 128;
  const int lane = tid & 63, wv = tid >> 6;
  const int wm = (wv >> 1) * 64, wn = (wv & 1) * 64;
  const int tr = tid >> 2, kb = (tid & 3) * 8;

  const float* asrc0 = x + token_of_row(row0 + tr) * 256 + kb;
  const float* asrc1 = x + token_of_row(row0 + tr + 64) * 256 + kb;
  const bf16_t* bsrc0 = Wt + (col0 + tr) * 256 + kb;
  const bf16_t* bsrc1 = Wt + (col0 + tr + 64) * 256 + kb;

  f32x4 acc[4][4];
#pragma unroll
  for (int m = 0; m < 4; ++m)
#pragma unroll
    for (int n = 0; n < 4; ++n) acc[m][n] = 0.f;

  for (int ks = 0; ks < 256; ks += 32) {
    __syncthreads();
    {
      const float* s0 = asrc0 + ks;
      const float* s1 = asrc1 + ks;
      f32x4 a0 = *(const f32x4*)s0, a1 = *(const f32x4*)(s0 + 4);
      f32x4 b0 = *(const f32x4*)s1, b1 = *(const f32x4*)(s1 + 4);
      bf16x8 oa, ob;
      oa[0]=(bf16_t)a0[0]; oa[1]=(bf16_t)a0[1]; oa[2]=(bf16_t)a0[2]; oa[3]=(bf16_t)a0[3];
      oa[4]=(bf16_t)a1[0]; oa[5]=(bf16_t)a1[1]; oa[6]=(bf16_t)a1[2]; oa[7]=(bf16_t)a1[3];
      ob[0]=(bf16_t)b0[0]; ob[1]=(bf16_t)b0[1]; ob[2]=(bf16_t)b0[2]; ob[3]=(bf16_t)b0[3];
      ob[4]=(bf16_t)b1[0]; ob[5]=(bf16_t)b1[1]; ob[6]=(bf16_t)b1[2]; ob[7]=(bf16_t)b1[3];
      *(bf16x8*)&As[tr * 32 + kb] = oa;
      *(bf16x8*)&As[(tr + 64) * 32 + kb] = ob;
      *(int4*)&Bs[tr * 32 + kb] = *(const int4*)(bsrc0 + ks);
      *(int4*)&Bs[(tr + 64) * 32 + kb] = *(const int4*)(bsrc1 + ks);
    }
    __syncthreads();
    bf16x8 aF[4], bF[4];
#pragma unroll
    for (int m = 0; m < 4; ++m)
      aF[m] = *(const bf16x8*)&As[(wm + m * 16 + (lane & 15)) * 32 + (lane >> 4) * 8];
#pragma unroll
    for (int n = 0; n < 4; ++n)
      bF[n] = *(const bf16x8*)&Bs[(wn + n * 16 + (lane & 15)) * 32 + (lane >> 4) * 8];
#pragma unroll
    for (int m = 0; m < 4; ++m)
#pragma unroll
      for (int n = 0; n < 4; ++n)
        acc[m][n] = __builtin_amdgcn_mfma_f32_16x16x32_bf16(aF[m], bF[n], acc[m][n], 0, 0, 0);
  }

  // C/D layout (verified): col = lane&15, row = (lane>>4)*4 + r
#pragma unroll
  for (int m = 0; m < 4; ++m) {
#pragma unroll
    for (int r = 0; r < 4; ++r) {
      int grow = row0 + wm + m * 16 + ((lane >> 4) << 2) + r;
      float* dst = QKV + grow * 768 + col0 + wn + (lane & 15);
#pragma unroll
      for (int n = 0; n < 4; ++n) dst[n * 16] = acc[m][n][r];
    }
  }
}

// ---------------- attn1: per (b, window, head), 64x64, d=32 ----------------
__global__ __launch_bounds__(64) void attn1_k(
    const float* __restrict__ QKV, const float* __restrict__ pos1,
    bf16_t* __restrict__ O) {
  __shared__ float P[64 * 65];
  const int bid = blockIdx.x;          // 4096 = b(4) * n(256) * h(4)
  const int h = bid & 3, n = (bid >> 2) & 255, b = bid >> 10;
  const int lane = threadIdx.x;
  const int rowbase = (b * 256 + n) * 64;

  // seed scores with positional bias (coalesced stage)
  const float* pp = pos1 + h * 4096;
  for (int r = 0; r < 64; ++r) P[r * 65 + lane] = pp[r * 64 + lane];
  __syncthreads();

  // q row for this lane, pre-scaled
  const float* qp = QKV + (size_t)(rowbase + lane) * 768 + h * 32;
  f32x4 q[8];
#pragma unroll
  for (int d = 0; d < 8; ++d) q[d] = (*(const f32x4*)(qp + 4 * d)) * SCALE_F;

  // QK^T: K rows are wave-uniform addresses
  for (int j = 0; j < 64; j += 2) {
    const float* kp0 = QKV + (size_t)(rowbase + j) * 768 + 256 + h * 32;
    const float* kp1 = kp0 + 768;
    f32x4 s0 = 0.f, s1 = 0.f;
#pragma unroll
    for (int d = 0; d < 8; ++d) {
      s0 += q[d] * (*(const f32x4*)(kp0 + 4 * d));
      s1 += q[d] * (*(const f32x4*)(kp1 + 4 * d));
    }
    P[lane * 65 + j]     += (s0[0] + s0[1]) + (s0[2] + s0[3]);
    P[lane * 65 + j + 1] += (s1[0] + s1[1]) + (s1[2] + s1[3]);
  }

  float mmax = -1e30f;
  for (int j = 0; j < 64; ++j) mmax = fmaxf(mmax, P[lane * 65 + j]);
  float l = 0.f;
  f32x4 o[8];
#pragma unroll
  for (int d = 0; d < 8; ++d) o[d] = 0.f;
  for (int j = 0; j < 64; ++j) {
    float e = __expf(P[lane * 65 + j] - mmax);
    l += e;
    const float* vp = QKV + (size_t)(rowbase + j) * 768 + 512 + h * 32;
#pragma unroll
    for (int d = 0; d < 8; ++d) o[d] += e * (*(const f32x4*)(vp + 4 * d));
  }
  float inv = 1.0f / l;
  bf16_t* op = O + (size_t)(rowbase + lane) * 256 + h * 32;
#pragma unroll
  for (int d = 0; d < 8; ++d) {
    f32x4 v = o[d] * inv;
    bf16x4 t;
    t[0]=(bf16_t)v[0]; t[1]=(bf16_t)v[1]; t[2]=(bf16_t)v[2]; t[3]=(bf16_t)v[3];
    *(bf16x4*)(op + d * 4) = t;
  }
}

// ---------------- attn2: per (b, m, head, qtile), seq=256 over windows ----------------
__global__ __launch_bounds__(64) void attn2_k(
    const float* __restrict__ QKV, const float* __restrict__ pos2,
    bf16_t* __restrict__ O) {
  __shared__ float P[64 * 65];
  const int bid = blockIdx.x;          // 4096 = b(4) * m(64) * h(4) * qt(4)
  const int qt = bid & 3, h = (bid >> 2) & 3, m = (bid >> 4) & 63, b = bid >> 10;
  const int lane = threadIdx.x;
  const int nq = qt * 64 + lane;                    // query window index
  const int qrow = (b * 256 + nq) * 64 + m;

  const float* qp = QKV + (size_t)qrow * 768 + 128 + h * 32;
  f32x4 q[8];
#pragma unroll
  for (int d = 0; d < 8; ++d) q[d] = (*(const f32x4*)(qp + 4 * d)) * SCALE_F;

  float mrun = -__builtin_inff(), l = 0.f;
  f32x4 o[8];
#pragma unroll
  for (int d = 0; d < 8; ++d) o[d] = 0.f;

  for (int t = 0; t < 4; ++t) {
    const int jb = t * 64;
    __syncthreads();
    // stage pos tile: rows i = qt*64 + r, cols jb + lane (coalesced)
    const float* pp = pos2 + (size_t)(h * 256 + qt * 64) * 256 + jb + lane;
    for (int r = 0; r < 64; ++r) P[r * 65 + lane] = pp[(size_t)r * 256];
    __syncthreads();

    for (int j = 0; j < 64; j += 2) {
      const int krow = (b * 256 + jb + j) * 64 + m;
      const float* kp0 = QKV + (size_t)krow * 768 + 384 + h * 32;  // K, ch 128..255
      const float* kp1 = kp0 + (size_t)64 * 768;                   // next window
      f32x4 s0 = 0.f, s1 = 0.f;
#pragma unroll
      for (int d = 0; d < 8; ++d) {
        s0 += q[d] * (*(const f32x4*)(kp0 + 4 * d));
        s1 += q[d] * (*(const f32x4*)(kp1 + 4 * d));
      }
      P[lane * 65 + j]     += (s0[0] + s0[1]) + (s0[2] + s0[3]);
      P[lane * 65 + j + 1] += (s1[0] + s1[1]) + (s1[2] + s1[3]);
    }

    float mt = -1e30f;
    for (int j = 0; j < 64; ++j) mt = fmaxf(mt, P[lane * 65 + j]);
    float mn = fmaxf(mrun, mt);
    float rs = __expf(mrun - mn);      // 0 on first tile (mrun = -inf)
    l *= rs;
#pragma unroll
    for (int d = 0; d < 8; ++d) o[d] *= rs;
    for (int j = 0; j < 64; ++j) {
      float e = __expf(P[lane * 65 + j] - mn);
      l += e;
      const int vrow = (b * 256 + jb + j) * 64 + m;
      const float* vp = QKV + (size_t)vrow * 768 + 640 + h * 32;   // V, ch 128..255
#pragma unroll
      for (int d = 0; d < 8; ++d) o[d] += e * (*(const f32x4*)(vp + 4 * d));
    }
    mrun = mn;
  }

  float inv = 1.0f / l;
  bf16_t* op = O + (size_t)qrow * 256 + 128 + h * 32;
#pragma unroll
  for (int d = 0; d < 8; ++d) {
    f32x4 v = o[d] * inv;
    bf16x4 t;
    t[0]=(bf16_t)v[0]; t[1]=(bf16_t)v[1]; t[2]=(bf16_t)v[2]; t[3]=(bf16_t)v[3];
    *(bf16x4*)(op + d * 4) = t;
  }
}

// ---------------- GEMM3: out = attnO @ Wo + bo, unwindowed ----------------
__global__ __launch_bounds__(256) void gemm_out_k(
    const bf16_t* __restrict__ A, const bf16_t* __restrict__ Wt,
    const float* __restrict__ bo, float* __restrict__ out) {
  __shared__ bf16_t As[128 * 32];
  __shared__ bf16_t Bs[128 * 32];
  const int tid = threadIdx.x;
  const int row0 = blockIdx.x * 128;
  const int col0 = blockIdx.y * 128;
  const int lane = tid & 63, wv = tid >> 6;
  const int wm = (wv >> 1) * 64, wn = (wv & 1) * 64;
  const int tr = tid >> 2, kb = (tid & 3) * 8;

  const bf16_t* asrc0 = A + (size_t)(row0 + tr) * 256 + kb;
  const bf16_t* asrc1 = A + (size_t)(row0 + tr + 64) * 256 + kb;
  const bf16_t* bsrc0 = Wt + (col0 + tr) * 256 + kb;
  const bf16_t* bsrc1 = Wt + (col0 + tr + 64) * 256 + kb;

  f32x4 acc[4][4];
#pragma unroll
  for (int m = 0; m < 4; ++m)
#pragma unroll
    for (int n = 0; n < 4; ++n) acc[m][n] = 0.f;

  for (int ks = 0; ks < 256; ks += 32) {
    __syncthreads();
    *(int4*)&As[tr * 32 + kb] = *(const int4*)(asrc0 + ks);
    *(int4*)&As[(tr + 64) * 32 + kb] = *(const int4*)(asrc1 + ks);
    *(int4*)&Bs[tr * 32 + kb] = *(const int4*)(bsrc0 + ks);
    *(int4*)&Bs[(tr + 64) * 32 + kb] = *(const int4*)(bsrc1 + ks);
    __syncthreads();
    bf16x8 aF[4], bF[4];
#pragma unroll
    for (int m = 0; m < 4; ++m)
      aF[m] = *(const bf16x8*)&As[(wm + m * 16 + (lane & 15)) * 32 + (lane >> 4) * 8];
#pragma unroll
    for (int n = 0; n < 4; ++n)
      bF[n] = *(const bf16x8*)&Bs[(wn + n * 16 + (lane & 15)) * 32 + (lane >> 4) * 8];
#pragma unroll
    for (int m = 0; m < 4; ++m)
#pragma unroll
      for (int n = 0; n < 4; ++n)
        acc[m][n] = __builtin_amdgcn_mfma_f32_16x16x32_bf16(aF[m], bF[n], acc[m][n], 0, 0, 0);
  }

  float bias[4];
#pragma unroll
  for (int n = 0; n < 4; ++n) bias[n] = bo[col0 + wn + n * 16 + (lane & 15)];

#pragma unroll
  for (int m = 0; m < 4; ++m) {
#pragma unroll
    for (int r = 0; r < 4; ++r) {
      int grow = row0 + wm + m * 16 + ((lane >> 4) << 2) + r;
      int tok = token_of_row(grow);
      float* dst = out + (size_t)tok * 256 + col0 + wn + (lane & 15);
#pragma unroll
      for (int n = 0; n < 4; ++n) dst[n * 16] = acc[m][n][r] + bias[n];
    }
  }
}

extern "C" void kernel_launch(void* const* d_in, const int* in_sizes, int n_in,
                              void* d_out, int out_size, void* d_ws, size_t ws_size,
                              hipStream_t stream) {
  (void)in_sizes; (void)n_in; (void)out_size; (void)ws_size;
  const float* x    = (const float*)d_in[0];
  const float* Wq   = (const float*)d_in[1];
  const float* Wkv  = (const float*)d_in[2];
  const float* Wo   = (const float*)d_in[3];
  const float* bo   = (const float*)d_in[4];
  const float* pos1 = (const float*)d_in[5];
  const float* pos2 = (const float*)d_in[6];
  float* out = (float*)d_out;

  char* ws = (char*)d_ws;
  bf16_t* WqkvT = (bf16_t*)(ws);
  bf16_t* WoT   = (bf16_t*)(ws + 393216);
  float*  QKV   = (float*)(ws + 524288);
  bf16_t* attnO = (bf16_t*)(ws + 524288 + 201326592ull);

  prep_w_k<<<1024, 256, 0, stream>>>(Wq, Wkv, Wo, WqkvT, WoT);
  dim3 g1(512, 6);
  gemm_qkv_k<<<g1, 256, 0, stream>>>(x, WqkvT, QKV);
  attn1_k<<<4096, 64, 0, stream>>>(QKV, pos1, attnO);
  attn2_k<<<4096, 64, 0, stream>>>(QKV, pos2, attnO);
  dim3 g3(512, 2);
  gemm_out_k<<<g3, 256, 0, stream>>>(attnO, WoT, bo, out);
}

// Round 2
// 323.291 us; speedup vs baseline: 2.0104x; 2.0104x over previous
//
#include <hip/hip_runtime.h>
#include <hip/hip_bf16.h>
#include <stdint.h>

// HS-MSA: QKV proj (bf16 MFMA GEMM) -> MFMA flash attention (two windowed
// branches) -> out proj + bias + unwindow.
//
// ws layout (bytes):
//   [0,        393216)  WqkvT bf16 [768][256]
//   [393216,   524288)  WoT   bf16 [256][256]
//   [524288,   589824)  pos1T f32  [4][64][64]   (col-major: [h][j][i])
//   [589824,  1638400)  pos2T f32  [4][256][256] (col-major)
//   [1638400, 102301696) QKV  bf16 [65536][768]  windowed rows; Q:0-255 K:256-511 V:512-767
//   [102301696, 135856128) attnO bf16 [65536][256]

typedef float f32x4 __attribute__((ext_vector_type(4)));
typedef __bf16 bf16_t;
typedef __bf16 bf16x8 __attribute__((ext_vector_type(8)));
typedef __bf16 bf16x4 __attribute__((ext_vector_type(4)));

#define SCALE_F 0.17677669529663687f

__device__ __forceinline__ int token_of_row(int gr) {
  int b = gr >> 14, n = (gr >> 6) & 255, m = gr & 63;
  int h = ((n >> 4) << 3) + (m >> 3);
  int w = ((n & 15) << 3) + (m & 7);
  return ((b << 7) + h) * 128 + w;
}

// ---------------- prep: weight transpose+bf16, pos transposes ----------------
__global__ __launch_bounds__(256) void prep_k(
    const float* __restrict__ Wq, const float* __restrict__ Wkv,
    const float* __restrict__ Wo, const float* __restrict__ pos1,
    const float* __restrict__ pos2, bf16_t* __restrict__ WqkvT,
    bf16_t* __restrict__ WoT, float* __restrict__ pos1T,
    float* __restrict__ pos2T) {
  int tid = blockIdx.x * 256 + threadIdx.x;
  if (tid < 196608) {
    int k = tid / 768, c = tid % 768;
    float v = (c < 256) ? Wq[k * 256 + c] : Wkv[k * 512 + (c - 256)];
    WqkvT[c * 256 + k] = (bf16_t)v;
  } else if (tid < 262144) {
    int t = tid - 196608;
    int k = t >> 8, c = t & 255;
    WoT[c * 256 + k] = (bf16_t)Wo[k * 256 + c];
  } else if (tid < 278528) {
    int t = tid - 262144;                       // h(4) i(64) j(64)
    int h = t >> 12, i = (t >> 6) & 63, j = t & 63;
    pos1T[(h * 64 + j) * 64 + i] = pos1[t];
  } else if (tid < 540672) {
    int t = tid - 278528;                       // h(4) i(256) j(256)
    int h = t >> 16, i = (t >> 8) & 255, j = t & 255;
    pos2T[(h * 256 + j) * 256 + i] = pos2[t];
  }
}

// ---------------- GEMM1: QKV(bf16) = x @ [Wq|Wk|Wv], windowed rows ----------------
__global__ __launch_bounds__(256) void gemm_qkv_k(
    const float* __restrict__ x, const bf16_t* __restrict__ Wt,
    bf16_t* __restrict__ QKV) {
  __shared__ bf16_t As[128 * 32];
  __shared__ bf16_t Bs[128 * 32];
  const int tid = threadIdx.x;
  const int row0 = blockIdx.x * 128;
  const int col0 = blockIdx.y * 128;
  const int lane = tid & 63, wv = tid >> 6;
  const int wm = (wv >> 1) * 64, wn = (wv & 1) * 64;
  const int tr = tid >> 2, kb = (tid & 3) * 8;

  const float* asrc0 = x + token_of_row(row0 + tr) * 256 + kb;
  const float* asrc1 = x + token_of_row(row0 + tr + 64) * 256 + kb;
  const bf16_t* bsrc0 = Wt + (col0 + tr) * 256 + kb;
  const bf16_t* bsrc1 = Wt + (col0 + tr + 64) * 256 + kb;

  f32x4 acc[4][4];
#pragma unroll
  for (int m = 0; m < 4; ++m)
#pragma unroll
    for (int n = 0; n < 4; ++n) acc[m][n] = 0.f;

  for (int ks = 0; ks < 256; ks += 32) {
    __syncthreads();
    {
      const float* s0 = asrc0 + ks;
      const float* s1 = asrc1 + ks;
      f32x4 a0 = *(const f32x4*)s0, a1 = *(const f32x4*)(s0 + 4);
      f32x4 b0 = *(const f32x4*)s1, b1 = *(const f32x4*)(s1 + 4);
      bf16x8 oa, ob;
      oa[0]=(bf16_t)a0[0]; oa[1]=(bf16_t)a0[1]; oa[2]=(bf16_t)a0[2]; oa[3]=(bf16_t)a0[3];
      oa[4]=(bf16_t)a1[0]; oa[5]=(bf16_t)a1[1]; oa[6]=(bf16_t)a1[2]; oa[7]=(bf16_t)a1[3];
      ob[0]=(bf16_t)b0[0]; ob[1]=(bf16_t)b0[1]; ob[2]=(bf16_t)b0[2]; ob[3]=(bf16_t)b0[3];
      ob[4]=(bf16_t)b1[0]; ob[5]=(bf16_t)b1[1]; ob[6]=(bf16_t)b1[2]; ob[7]=(bf16_t)b1[3];
      *(bf16x8*)&As[tr * 32 + kb] = oa;
      *(bf16x8*)&As[(tr + 64) * 32 + kb] = ob;
      *(int4*)&Bs[tr * 32 + kb] = *(const int4*)(bsrc0 + ks);
      *(int4*)&Bs[(tr + 64) * 32 + kb] = *(const int4*)(bsrc1 + ks);
    }
    __syncthreads();
    bf16x8 aF[4], bF[4];
#pragma unroll
    for (int m = 0; m < 4; ++m)
      aF[m] = *(const bf16x8*)&As[(wm + m * 16 + (lane & 15)) * 32 + (lane >> 4) * 8];
#pragma unroll
    for (int n = 0; n < 4; ++n)
      bF[n] = *(const bf16x8*)&Bs[(wn + n * 16 + (lane & 15)) * 32 + (lane >> 4) * 8];
#pragma unroll
    for (int m = 0; m < 4; ++m)
#pragma unroll
      for (int n = 0; n < 4; ++n)
        acc[m][n] = __builtin_amdgcn_mfma_f32_16x16x32_bf16(aF[m], bF[n], acc[m][n], 0, 0, 0);
  }

#pragma unroll
  for (int m = 0; m < 4; ++m) {
#pragma unroll
    for (int r = 0; r < 4; ++r) {
      int grow = row0 + wm + m * 16 + ((lane >> 4) << 2) + r;
      bf16_t* dst = QKV + (size_t)grow * 768 + col0 + wn + (lane & 15);
#pragma unroll
      for (int n = 0; n < 4; ++n) dst[n * 16] = (bf16_t)acc[m][n][r];
    }
  }
}

// ---------------- attn1: block=(b,n), wave=head, 64x64 single tile ----------------
__global__ __launch_bounds__(256, 2) void attn1_k(
    const bf16_t* __restrict__ QKV, const float* __restrict__ pos1T,
    bf16_t* __restrict__ O) {
  __shared__ char lds[65536];       // Ks [4][64][32], Vs [4][64][32], P [4][64][64]
  bf16_t* Ks = (bf16_t*)lds;
  bf16_t* Vs = (bf16_t*)(lds + 16384);
  const int bid = blockIdx.x;
  const int n = bid & 255, b = bid >> 8;
  const int tid = threadIdx.x;
  const int lane = tid & 63, h = tid >> 6;
  const int g = lane >> 4, c = lane & 15;
  char* Pw = lds + 32768 + h * 8192;
  const size_t rowbase = (size_t)(b * 256 + n) * 64;
  const char* base = (const char*)QKV + rowbase * 1536;

#pragma unroll
  for (int it = 0; it < 4; ++it) {
    int idx = it * 256 + tid;
    int hh = idx >> 8, key = (idx >> 2) & 63, ch = idx & 3;
    const char* rowp = base + (size_t)key * 1536;
    int4 kk = *(const int4*)(rowp + 512  + 64 * hh + ch * 16);
    int4 vv = *(const int4*)(rowp + 1024 + 64 * hh + ch * 16);
    int koff = (hh * 64 + key) * 64 + ch * 16;
    *(int4*)((char*)Ks + (koff ^ ((key & 3) << 4))) = kk;
    *(int4*)((char*)Vs + (koff ^ ((key & 7) << 4))) = vv;
  }

  bf16x8 qa[4];
  {
    const char* qbase = base + 64 * h + g * 16;
#pragma unroll
    for (int mf = 0; mf < 4; ++mf)
      qa[mf] = *(const bf16x8*)(qbase + (size_t)(c + 16 * mf) * 1536);
  }
  __syncthreads();

  f32x4 S[4][4];
#pragma unroll
  for (int mf = 0; mf < 4; ++mf)
#pragma unroll
    for (int nf = 0; nf < 4; ++nf) S[mf][nf] = 0.f;

#pragma unroll
  for (int nf = 0; nf < 4; ++nf) {
    int key = 16 * nf + c;
    int off = ((h * 64 + key) * 64 + g * 16) ^ ((key & 3) << 4);
    bf16x8 kbf = *(const bf16x8*)((const char*)Ks + off);
#pragma unroll
    for (int mf = 0; mf < 4; ++mf)
      S[mf][nf] = __builtin_amdgcn_mfma_f32_16x16x32_bf16(qa[mf], kbf, S[mf][nf], 0, 0, 0);
  }

#pragma unroll
  for (int nf = 0; nf < 4; ++nf) {
    int col = 16 * nf + c;
    const float* pp = pos1T + (h * 64 + col) * 64;
#pragma unroll
    for (int mf = 0; mf < 4; ++mf) {
      f32x4 pv = *(const f32x4*)(pp + 16 * mf + 4 * g);
      S[mf][nf] = S[mf][nf] * SCALE_F + pv;
    }
  }

  float inv_l[4][4];
#pragma unroll
  for (int mf = 0; mf < 4; ++mf) {
#pragma unroll
    for (int r = 0; r < 4; ++r) {
      float t = fmaxf(fmaxf(S[mf][0][r], S[mf][1][r]), fmaxf(S[mf][2][r], S[mf][3][r]));
      t = fmaxf(t, __shfl_xor(t, 1));
      t = fmaxf(t, __shfl_xor(t, 2));
      t = fmaxf(t, __shfl_xor(t, 4));
      t = fmaxf(t, __shfl_xor(t, 8));
      float p0 = __expf(S[mf][0][r] - t), p1 = __expf(S[mf][1][r] - t);
      float p2 = __expf(S[mf][2][r] - t), p3 = __expf(S[mf][3][r] - t);
      float ls = (p0 + p1) + (p2 + p3);
      ls += __shfl_xor(ls, 1); ls += __shfl_xor(ls, 2);
      ls += __shfl_xor(ls, 4); ls += __shfl_xor(ls, 8);
      float inv = 1.0f / ls;
      inv_l[mf][r] = 1.0f;   // P pre-normalized
      bf16x4 pb;
      pb[0] = (bf16_t)(p0 * inv); pb[1] = (bf16_t)(p1 * inv);
      pb[2] = (bf16_t)(p2 * inv); pb[3] = (bf16_t)(p3 * inv);
      int row = 16 * mf + 4 * g + r;
      *(bf16x4*)(Pw + ((row * 128 + 8 * c) ^ ((row & 7) << 4))) = pb;
    }
  }

  f32x4 Ofr[4][2];
#pragma unroll
  for (int mf = 0; mf < 4; ++mf) { Ofr[mf][0] = 0.f; Ofr[mf][1] = 0.f; }

#pragma unroll
  for (int kf = 0; kf < 2; ++kf) {
    bf16x8 pa[4];
#pragma unroll
    for (int mf = 0; mf < 4; ++mf) {
      int row = c + 16 * mf;
      pa[mf] = *(const bf16x8*)(Pw + ((row * 128 + 64 * kf + 16 * g) ^ ((row & 7) << 4)));
    }
#pragma unroll
    for (int nf = 0; nf < 2; ++nf) {
      bf16x8 vb;
#pragma unroll
      for (int j = 0; j < 8; ++j) {
        int key = 16 * (j & 3) + 8 * kf + 2 * g + (j >> 2);
        int off = ((h * 64 + key) * 64 + 2 * (c + 16 * nf)) ^ ((key & 7) << 4);
        vb[j] = *(const bf16_t*)((const char*)Vs + off);
      }
#pragma unroll
      for (int mf = 0; mf < 4; ++mf)
        Ofr[mf][nf] = __builtin_amdgcn_mfma_f32_16x16x32_bf16(pa[mf], vb, Ofr[mf][nf], 0, 0, 0);
    }
  }

#pragma unroll
  for (int mf = 0; mf < 4; ++mf)
#pragma unroll
    for (int r = 0; r < 4; ++r) {
      int rl = 16 * mf + 4 * g + r;
      bf16_t* op = O + (rowbase + rl) * 256 + 32 * h + c;
      op[0]  = (bf16_t)Ofr[mf][0][r];
      op[16] = (bf16_t)Ofr[mf][1][r];
    }
}

// ---------------- attn2: block=(b,m,h), wave=qtile, flash over 4 key tiles ----------------
__global__ __launch_bounds__(256, 2) void attn2_k(
    const bf16_t* __restrict__ QKV, const float* __restrict__ pos2T,
    bf16_t* __restrict__ O) {
  __shared__ char lds[65536];       // Ks [256][32], Vs [256][32], P [4][64][64]
  bf16_t* Ks = (bf16_t*)lds;
  bf16_t* Vs = (bf16_t*)(lds + 16384);
  const int bid = blockIdx.x;
  const int h = bid & 3, m = (bid >> 2) & 63, b = bid >> 8;
  const int tid = threadIdx.x;
  const int lane = tid & 63, wid = tid >> 6;
  const int g = lane >> 4, c = lane & 15;
  char* Pw = lds + 32768 + wid * 8192;
  const char* base = (const char*)QKV + (size_t)(b * 256 * 64 + m) * 1536;

#pragma unroll
  for (int it = 0; it < 4; ++it) {
    int idx = it * 256 + tid;
    int key = idx >> 2, ch = idx & 3;
    const char* rowp = base + (size_t)key * (64 * 1536);
    int4 kk = *(const int4*)(rowp + 768  + 64 * h + ch * 16);
    int4 vv = *(const int4*)(rowp + 1280 + 64 * h + ch * 16);
    int koff = key * 64 + ch * 16;
    *(int4*)((char*)Ks + (koff ^ ((key & 3) << 4))) = kk;
    *(int4*)((char*)Vs + (koff ^ ((key & 7) << 4))) = vv;
  }

  bf16x8 qa[4];
  {
    const char* qbase = (const char*)QKV + 256 + 64 * h + g * 16;
#pragma unroll
    for (int mf = 0; mf < 4; ++mf) {
      size_t qrow = (size_t)((b * 256 + wid * 64 + c + 16 * mf) * 64 + m);
      qa[mf] = *(const bf16x8*)(qbase + qrow * 1536);
    }
  }
  __syncthreads();

  f32x4 Ofr[4][2];
  float m_run[4][4], l_run[4][4];
#pragma unroll
  for (int mf = 0; mf < 4; ++mf) {
    Ofr[mf][0] = 0.f; Ofr[mf][1] = 0.f;
#pragma unroll
    for (int r = 0; r < 4; ++r) { m_run[mf][r] = -3.0e38f; l_run[mf][r] = 0.f; }
  }

  for (int kt = 0; kt < 4; ++kt) {
    f32x4 S[4][4];
#pragma unroll
    for (int mf = 0; mf < 4; ++mf)
#pragma unroll
      for (int nf = 0; nf < 4; ++nf) S[mf][nf] = 0.f;

#pragma unroll
    for (int nf = 0; nf < 4; ++nf) {
      int key = kt * 64 + 16 * nf + c;
      int off = (key * 64 + g * 16) ^ ((key & 3) << 4);
      bf16x8 kbf = *(const bf16x8*)((const char*)Ks + off);
#pragma unroll
      for (int mf = 0; mf < 4; ++mf)
        S[mf][nf] = __builtin_amdgcn_mfma_f32_16x16x32_bf16(qa[mf], kbf, S[mf][nf], 0, 0, 0);
    }

#pragma unroll
    for (int nf = 0; nf < 4; ++nf) {
      int col = kt * 64 + 16 * nf + c;
      const float* pp = pos2T + ((h * 256 + col) * 256 + wid * 64);
#pragma unroll
      for (int mf = 0; mf < 4; ++mf) {
        f32x4 pv = *(const f32x4*)(pp + 16 * mf + 4 * g);
        S[mf][nf] = S[mf][nf] * SCALE_F + pv;
      }
    }

#pragma unroll
    for (int mf = 0; mf < 4; ++mf) {
#pragma unroll
      for (int r = 0; r < 4; ++r) {
        float t = fmaxf(fmaxf(S[mf][0][r], S[mf][1][r]), fmaxf(S[mf][2][r], S[mf][3][r]));
        t = fmaxf(t, __shfl_xor(t, 1));
        t = fmaxf(t, __shfl_xor(t, 2));
        t = fmaxf(t, __shfl_xor(t, 4));
        t = fmaxf(t, __shfl_xor(t, 8));
        float mn = fmaxf(m_run[mf][r], t);
        float rsc = __expf(m_run[mf][r] - mn);
        m_run[mf][r] = mn;
        float p0 = __expf(S[mf][0][r] - mn), p1 = __expf(S[mf][1][r] - mn);
        float p2 = __expf(S[mf][2][r] - mn), p3 = __expf(S[mf][3][r] - mn);
        float ls = (p0 + p1) + (p2 + p3);
        ls += __shfl_xor(ls, 1); ls += __shfl_xor(ls, 2);
        ls += __shfl_xor(ls, 4); ls += __shfl_xor(ls, 8);
        l_run[mf][r] = l_run[mf][r] * rsc + ls;
        Ofr[mf][0][r] *= rsc;
        Ofr[mf][1][r] *= rsc;
        bf16x4 pb;
        pb[0] = (bf16_t)p0; pb[1] = (bf16_t)p1; pb[2] = (bf16_t)p2; pb[3] = (bf16_t)p3;
        int row = 16 * mf + 4 * g + r;
        *(bf16x4*)(Pw + ((row * 128 + 8 * c) ^ ((row & 7) << 4))) = pb;
      }
    }

#pragma unroll
    for (int kf = 0; kf < 2; ++kf) {
      bf16x8 pa[4];
#pragma unroll
      for (int mf = 0; mf < 4; ++mf) {
        int row = c + 16 * mf;
        pa[mf] = *(const bf16x8*)(Pw + ((row * 128 + 64 * kf + 16 * g) ^ ((row & 7) << 4)));
      }
#pragma unroll
      for (int nf = 0; nf < 2; ++nf) {
        bf16x8 vb;
#pragma unroll
        for (int j = 0; j < 8; ++j) {
          int key = kt * 64 + 16 * (j & 3) + 8 * kf + 2 * g + (j >> 2);
          int off = (key * 64 + 2 * (c + 16 * nf)) ^ ((key & 7) << 4);
          vb[j] = *(const bf16_t*)((const char*)Vs + off);
        }
#pragma unroll
        for (int mf = 0; mf < 4; ++mf)
          Ofr[mf][nf] = __builtin_amdgcn_mfma_f32_16x16x32_bf16(pa[mf], vb, Ofr[mf][nf], 0, 0, 0);
      }
    }
  }

#pragma unroll
  for (int mf = 0; mf < 4; ++mf)
#pragma unroll
    for (int r = 0; r < 4; ++r) {
      float inv = 1.0f / l_run[mf][r];
      int rl = 16 * mf + 4 * g + r;
      size_t qrow = (size_t)((b * 256 + wid * 64 + rl) * 64 + m);
      bf16_t* op = O + qrow * 256 + 128 + 32 * h + c;
      op[0]  = (bf16_t)(Ofr[mf][0][r] * inv);
      op[16] = (bf16_t)(Ofr[mf][1][r] * inv);
    }
}

// ---------------- GEMM3: out = attnO @ Wo + bo, unwindowed ----------------
__global__ __launch_bounds__(256) void gemm_out_k(
    const bf16_t* __restrict__ A, const bf16_t* __restrict__ Wt,
    const float* __restrict__ bo, float* __restrict__ out) {
  __shared__ bf16_t As[128 * 32];
  __shared__ bf16_t Bs[128 * 32];
  const int tid = threadIdx.x;
  const int row0 = blockIdx.x * 128;
  const int col0 = blockIdx.y * 128;
  const int lane = tid & 63, wv = tid >> 6;
  const int wm = (wv >> 1) * 64, wn = (wv & 1) * 64;
  const int tr = tid >> 2, kb = (tid & 3) * 8;

  const bf16_t* asrc0 = A + (size_t)(row0 + tr) * 256 + kb;
  const bf16_t* asrc1 = A + (size_t)(row0 + tr + 64) * 256 + kb;
  const bf16_t* bsrc0 = Wt + (col0 + tr) * 256 + kb;
  const bf16_t* bsrc1 = Wt + (col0 + tr + 64) * 256 + kb;

  f32x4 acc[4][4];
#pragma unroll
  for (int m = 0; m < 4; ++m)
#pragma unroll
    for (int n = 0; n < 4; ++n) acc[m][n] = 0.f;

  for (int ks = 0; ks < 256; ks += 32) {
    __syncthreads();
    *(int4*)&As[tr * 32 + kb] = *(const int4*)(asrc0 + ks);
    *(int4*)&As[(tr + 64) * 32 + kb] = *(const int4*)(asrc1 + ks);
    *(int4*)&Bs[tr * 32 + kb] = *(const int4*)(bsrc0 + ks);
    *(int4*)&Bs[(tr + 64) * 32 + kb] = *(const int4*)(bsrc1 + ks);
    __syncthreads();
    bf16x8 aF[4], bF[4];
#pragma unroll
    for (int m = 0; m < 4; ++m)
      aF[m] = *(const bf16x8*)&As[(wm + m * 16 + (lane & 15)) * 32 + (lane >> 4) * 8];
#pragma unroll
    for (int n = 0; n < 4; ++n)
      bF[n] = *(const bf16x8*)&Bs[(wn + n * 16 + (lane & 15)) * 32 + (lane >> 4) * 8];
#pragma unroll
    for (int m = 0; m < 4; ++m)
#pragma unroll
      for (int n = 0; n < 4; ++n)
        acc[m][n] = __builtin_amdgcn_mfma_f32_16x16x32_bf16(aF[m], bF[n], acc[m][n], 0, 0, 0);
  }

  float bias[4];
#pragma unroll
  for (int n = 0; n < 4; ++n) bias[n] = bo[col0 + wn + n * 16 + (lane & 15)];

#pragma unroll
  for (int m = 0; m < 4; ++m) {
#pragma unroll
    for (int r = 0; r < 4; ++r) {
      int grow = row0 + wm + m * 16 + ((lane >> 4) << 2) + r;
      int tok = token_of_row(grow);
      float* dst = out + (size_t)tok * 256 + col0 + wn + (lane & 15);
#pragma unroll
      for (int n = 0; n < 4; ++n) dst[n * 16] = acc[m][n][r] + bias[n];
    }
  }
}

extern "C" void kernel_launch(void* const* d_in, const int* in_sizes, int n_in,
                              void* d_out, int out_size, void* d_ws, size_t ws_size,
                              hipStream_t stream) {
  (void)in_sizes; (void)n_in; (void)out_size; (void)ws_size;
  const float* x    = (const float*)d_in[0];
  const float* Wq   = (const float*)d_in[1];
  const float* Wkv  = (const float*)d_in[2];
  const float* Wo   = (const float*)d_in[3];
  const float* bo   = (const float*)d_in[4];
  const float* pos1 = (const float*)d_in[5];
  const float* pos2 = (const float*)d_in[6];
  float* out = (float*)d_out;

  char* ws = (char*)d_ws;
  bf16_t* WqkvT = (bf16_t*)(ws);
  bf16_t* WoT   = (bf16_t*)(ws + 393216);
  float*  pos1T = (float*)(ws + 524288);
  float*  pos2T = (float*)(ws + 589824);
  bf16_t* QKVb  = (bf16_t*)(ws + 1638400);
  bf16_t* attnO = (bf16_t*)(ws + 102301696ull);

  prep_k<<<2112, 256, 0, stream>>>(Wq, Wkv, Wo, pos1, pos2, WqkvT, WoT, pos1T, pos2T);
  dim3 g1(512, 6);
  gemm_qkv_k<<<g1, 256, 0, stream>>>(x, WqkvT, QKVb);
  attn1_k<<<1024, 256, 0, stream>>>(QKVb, pos1T, attnO);
  attn2_k<<<1024, 256, 0, stream>>>(QKVb, pos2T, attnO);
  dim3 g3(512, 2);
  gemm_out_k<<<g3, 256, 0, stream>>>(attnO, WoT, bo, out);
}

// Round 4
// 297.113 us; speedup vs baseline: 2.1876x; 1.0881x over previous
//
#include <hip/hip_runtime.h>
#include <hip/hip_bf16.h>
#include <stdint.h>

// HS-MSA: QKV proj (bf16 MFMA GEMM) -> swapped-operand MFMA flash attention
// (S^T = K*Q^T so softmax is lane-parallel over q) -> out proj + bias.
//
// ws layout (bytes):
//   [0,        393216)   WqkvT bf16 [768][256]
//   [393216,   524288)   WoT   bf16 [256][256]
//   [524288,  101187584) QKV   bf16 [65536][768] windowed rows; Q:0-255 K:256-511 V:512-767
//   [101187584, 134742016) attnO bf16 [65536][256]

typedef float f32x4 __attribute__((ext_vector_type(4)));
typedef __bf16 bf16_t;
typedef __bf16 bf16x8 __attribute__((ext_vector_type(8)));
typedef __bf16 bf16x4 __attribute__((ext_vector_type(4)));
typedef __bf16 bf16x2 __attribute__((ext_vector_type(2)));

#define SCALE_F 0.17677669529663687f

__device__ __forceinline__ int token_of_row(int gr) {
  int b = gr >> 14, n = (gr >> 6) & 255, m = gr & 63;
  int h = ((n >> 4) << 3) + (m >> 3);
  int w = ((n & 15) << 3) + (m & 7);
  return ((b << 7) + h) * 128 + w;
}

// ---------------- prep: weight transpose + bf16 ----------------
__global__ __launch_bounds__(256) void prep_k(
    const float* __restrict__ Wq, const float* __restrict__ Wkv,
    const float* __restrict__ Wo, bf16_t* __restrict__ WqkvT,
    bf16_t* __restrict__ WoT) {
  int tid = blockIdx.x * 256 + threadIdx.x;
  if (tid < 196608) {
    int k = tid / 768, c = tid % 768;
    float v = (c < 256) ? Wq[k * 256 + c] : Wkv[k * 512 + (c - 256)];
    WqkvT[c * 256 + k] = (bf16_t)v;
  } else if (tid < 262144) {
    int t = tid - 196608;
    int k = t >> 8, c = t & 255;
    WoT[c * 256 + k] = (bf16_t)Wo[k * 256 + c];
  }
}

// ---------------- GEMM1: QKV(bf16) = x @ [Wq|Wk|Wv], windowed rows ----------------
__global__ __launch_bounds__(256) void gemm_qkv_k(
    const float* __restrict__ x, const bf16_t* __restrict__ Wt,
    bf16_t* __restrict__ QKV) {
  __shared__ bf16_t As[128 * 32];
  __shared__ bf16_t Bs[128 * 32];
  const int tid = threadIdx.x;
  const int row0 = blockIdx.x * 128;
  const int col0 = blockIdx.y * 128;
  const int lane = tid & 63, wv = tid >> 6;
  const int wm = (wv >> 1) * 64, wn = (wv & 1) * 64;
  const int tr = tid >> 2, kb = (tid & 3) * 8;

  const float* asrc0 = x + token_of_row(row0 + tr) * 256 + kb;
  const float* asrc1 = x + token_of_row(row0 + tr + 64) * 256 + kb;
  const bf16_t* bsrc0 = Wt + (col0 + tr) * 256 + kb;
  const bf16_t* bsrc1 = Wt + (col0 + tr + 64) * 256 + kb;

  f32x4 acc[4][4];
#pragma unroll
  for (int m = 0; m < 4; ++m)
#pragma unroll
    for (int n = 0; n < 4; ++n) acc[m][n] = 0.f;

  for (int ks = 0; ks < 256; ks += 32) {
    __syncthreads();
    {
      const float* s0 = asrc0 + ks;
      const float* s1 = asrc1 + ks;
      f32x4 a0 = *(const f32x4*)s0, a1 = *(const f32x4*)(s0 + 4);
      f32x4 b0 = *(const f32x4*)s1, b1 = *(const f32x4*)(s1 + 4);
      bf16x8 oa, ob;
      oa[0]=(bf16_t)a0[0]; oa[1]=(bf16_t)a0[1]; oa[2]=(bf16_t)a0[2]; oa[3]=(bf16_t)a0[3];
      oa[4]=(bf16_t)a1[0]; oa[5]=(bf16_t)a1[1]; oa[6]=(bf16_t)a1[2]; oa[7]=(bf16_t)a1[3];
      ob[0]=(bf16_t)b0[0]; ob[1]=(bf16_t)b0[1]; ob[2]=(bf16_t)b0[2]; ob[3]=(bf16_t)b0[3];
      ob[4]=(bf16_t)b1[0]; ob[5]=(bf16_t)b1[1]; ob[6]=(bf16_t)b1[2]; ob[7]=(bf16_t)b1[3];
      *(bf16x8*)&As[tr * 32 + kb] = oa;
      *(bf16x8*)&As[(tr + 64) * 32 + kb] = ob;
      *(int4*)&Bs[tr * 32 + kb] = *(const int4*)(bsrc0 + ks);
      *(int4*)&Bs[(tr + 64) * 32 + kb] = *(const int4*)(bsrc1 + ks);
    }
    __syncthreads();
    bf16x8 aF[4], bF[4];
#pragma unroll
    for (int m = 0; m < 4; ++m)
      aF[m] = *(const bf16x8*)&As[(wm + m * 16 + (lane & 15)) * 32 + (lane >> 4) * 8];
#pragma unroll
    for (int n = 0; n < 4; ++n)
      bF[n] = *(const bf16x8*)&Bs[(wn + n * 16 + (lane & 15)) * 32 + (lane >> 4) * 8];
#pragma unroll
    for (int m = 0; m < 4; ++m)
#pragma unroll
      for (int n = 0; n < 4; ++n)
        acc[m][n] = __builtin_amdgcn_mfma_f32_16x16x32_bf16(aF[m], bF[n], acc[m][n], 0, 0, 0);
  }

#pragma unroll
  for (int m = 0; m < 4; ++m) {
#pragma unroll
    for (int r = 0; r < 4; ++r) {
      int grow = row0 + wm + m * 16 + ((lane >> 4) << 2) + r;
      bf16_t* dst = QKV + (size_t)grow * 768 + col0 + wn + (lane & 15);
#pragma unroll
      for (int n = 0; n < 4; ++n) dst[n * 16] = (bf16_t)acc[m][n][r];
    }
  }
}

// ---------------- attn1: block=(b,n), wave=head; S^T=K*Q^T, O^T=V^T*P^T ----------------
// LDS: K [4h][64key][80B] @0 ; Vt [4h][32d][144B] @20480 ; P per-wave 2KB @38912
__global__ __launch_bounds__(256, 3) void attn1_k(
    const bf16_t* __restrict__ QKV, const float* __restrict__ pos1,
    bf16_t* __restrict__ O) {
  __shared__ char lds[47104];
  const int bid = blockIdx.x;
  const int n = bid & 255, b = bid >> 8;
  const int tid = threadIdx.x;
  const int lane = tid & 63, h = tid >> 6;
  const int g = lane >> 4, c = lane & 15;
  char* Pw = lds + 38912 + h * 2048;
  const size_t rowbase = (size_t)(b * 256 + n) * 64;
  const char* base = (const char*)QKV + rowbase * 1536;

  // stage K (head-sliced rows, 64B each)
#pragma unroll
  for (int it = 0; it < 4; ++it) {
    int idx = it * 256 + tid;
    int hh = idx >> 8, key = (idx >> 2) & 63, ch4 = idx & 3;
    int4 kk = *(const int4*)(base + (size_t)key * 1536 + 512 + 64 * hh + ch4 * 16);
    *(int4*)(lds + (hh * 64 + key) * 80 + ch4 * 16) = kk;
  }
  // stage V transposed: Vt[h][d][m]
#pragma unroll
  for (int it = 0; it < 4; ++it) {
    int idx = it * 256 + tid;
    int hh = idx >> 8, mm = (idx >> 2) & 63, dq = idx & 3;
    bf16x8 vv = *(const bf16x8*)(base + (size_t)mm * 1536 + 1024 + 64 * hh + dq * 16);
#pragma unroll
    for (int j = 0; j < 8; ++j)
      *(bf16_t*)(lds + 20480 + hh * 4608 + (dq * 8 + j) * 144 + mm * 2) = vv[j];
  }

  // Q B-frags: q = lane&15
  bf16x8 qa[4];
#pragma unroll
  for (int qf = 0; qf < 4; ++qf)
    qa[qf] = *(const bf16x8*)(base + (size_t)(qf * 16 + c) * 1536 + 64 * h + 16 * g);
  __syncthreads();

  // K A-frags + V^T A-frags
  bf16x8 kfr[4];
#pragma unroll
  for (int kf = 0; kf < 4; ++kf)
    kfr[kf] = *(const bf16x8*)(lds + (h * 64 + kf * 16 + c) * 80 + 16 * g);
  bf16x8 vfr[2][2];
#pragma unroll
  for (int kb = 0; kb < 2; ++kb)
#pragma unroll
    for (int dt = 0; dt < 2; ++dt)
      vfr[kb][dt] = *(const bf16x8*)(lds + 20480 + h * 4608 + (dt * 16 + c) * 144 + kb * 64 + g * 16);

  f32x4 Ov[2][4];
#pragma unroll
  for (int dt = 0; dt < 2; ++dt)
#pragma unroll
    for (int qf = 0; qf < 4; ++qf) Ov[dt][qf] = 0.f;

#pragma unroll
  for (int qf = 0; qf < 4; ++qf) {
    f32x4 S[4];
#pragma unroll
    for (int kf = 0; kf < 4; ++kf) {
      S[kf] = 0.f;
      S[kf] = __builtin_amdgcn_mfma_f32_16x16x32_bf16(kfr[kf], qa[qf], S[kf], 0, 0, 0);
    }
    // bias: pos1[h][q][key], key contiguous over r
    const float* pp = pos1 + ((h * 64 + qf * 16 + c) * 64 + 4 * g);
#pragma unroll
    for (int kf = 0; kf < 4; ++kf) {
      f32x4 pv = *(const f32x4*)(pp + kf * 16);
      S[kf] = S[kf] * SCALE_F + pv;
    }
    float tm0 = fmaxf(fmaxf(S[0][0], S[0][1]), fmaxf(S[0][2], S[0][3]));
    float tm1 = fmaxf(fmaxf(S[1][0], S[1][1]), fmaxf(S[1][2], S[1][3]));
    float tm2 = fmaxf(fmaxf(S[2][0], S[2][1]), fmaxf(S[2][2], S[2][3]));
    float tm3 = fmaxf(fmaxf(S[3][0], S[3][1]), fmaxf(S[3][2], S[3][3]));
    float t = fmaxf(fmaxf(tm0, tm1), fmaxf(tm2, tm3));
    t = fmaxf(t, __shfl_xor(t, 16));
    t = fmaxf(t, __shfl_xor(t, 32));
    float ls = 0.f;
#pragma unroll
    for (int kf = 0; kf < 4; ++kf)
#pragma unroll
      for (int r = 0; r < 4; ++r) {
        S[kf][r] = __expf(S[kf][r] - t);
        ls += S[kf][r];
      }
    ls += __shfl_xor(ls, 16);
    ls += __shfl_xor(ls, 32);
    float inv = 1.0f / ls;
    // pack normalized P into per-wave LDS [16q][64key], XOR-swizzled
#pragma unroll
    for (int kf = 0; kf < 4; ++kf)
#pragma unroll
      for (int p = 0; p < 2; ++p) {
        bf16x2 w;
        w[0] = (bf16_t)(S[kf][2 * p] * inv);
        w[1] = (bf16_t)(S[kf][2 * p + 1] * inv);
        int byteo = c * 128 + kf * 32 + g * 8 + p * 4;
        *(bf16x2*)(Pw + (byteo ^ ((c & 7) << 4))) = w;
      }
    bf16x8 pb0 = *(const bf16x8*)(Pw + ((c * 128 + g * 16) ^ ((c & 7) << 4)));
    bf16x8 pb1 = *(const bf16x8*)(Pw + ((c * 128 + 64 + g * 16) ^ ((c & 7) << 4)));
    Ov[0][qf] = __builtin_amdgcn_mfma_f32_16x16x32_bf16(vfr[0][0], pb0, Ov[0][qf], 0, 0, 0);
    Ov[1][qf] = __builtin_amdgcn_mfma_f32_16x16x32_bf16(vfr[0][1], pb0, Ov[1][qf], 0, 0, 0);
    Ov[0][qf] = __builtin_amdgcn_mfma_f32_16x16x32_bf16(vfr[1][0], pb1, Ov[0][qf], 0, 0, 0);
    Ov[1][qf] = __builtin_amdgcn_mfma_f32_16x16x32_bf16(vfr[1][1], pb1, Ov[1][qf], 0, 0, 0);
  }

  // store: lane holds O^T[d = dt*16+4g+r][q = qf*16+c]
#pragma unroll
  for (int qf = 0; qf < 4; ++qf)
#pragma unroll
    for (int dt = 0; dt < 2; ++dt) {
      int row = (b * 256 + n) * 64 + qf * 16 + c;
      bf16x4 ov;
      ov[0] = (bf16_t)Ov[dt][qf][0]; ov[1] = (bf16_t)Ov[dt][qf][1];
      ov[2] = (bf16_t)Ov[dt][qf][2]; ov[3] = (bf16_t)Ov[dt][qf][3];
      *(bf16x4*)(O + (size_t)row * 256 + 32 * h + dt * 16 + 4 * g) = ov;
    }
}

// ---------------- attn2: block=(b,m,h), wave=qtile; flash over 4 key tiles ----------------
// LDS: K [256key][80B] @0 ; Vt [32d][528B] @20480 ; P per-wave 2KB @37376
__global__ __launch_bounds__(256, 3) void attn2_k(
    const bf16_t* __restrict__ QKV, const float* __restrict__ pos2,
    bf16_t* __restrict__ O) {
  __shared__ char lds[45568];
  const int bid = blockIdx.x;
  const int h = bid & 3, m = (bid >> 2) & 63, b = bid >> 8;
  const int tid = threadIdx.x;
  const int lane = tid & 63, wid = tid >> 6;
  const int g = lane >> 4, c = lane & 15;
  char* Pw = lds + 37376 + wid * 2048;
  const char* kvbase = (const char*)QKV + (size_t)(b * 16384 + m) * 1536;

  // stage K (keys = windows, head slice 64B each)
#pragma unroll
  for (int it = 0; it < 4; ++it) {
    int idx = it * 256 + tid;
    int key = idx >> 2, ch4 = idx & 3;
    int4 kk = *(const int4*)(kvbase + (size_t)key * 98304 + 768 + 64 * h + ch4 * 16);
    *(int4*)(lds + key * 80 + ch4 * 16) = kk;
  }
  // stage V transposed: Vt[d][key]
#pragma unroll
  for (int it = 0; it < 4; ++it) {
    int idx = it * 256 + tid;
    int nn = idx >> 2, dq = idx & 3;
    bf16x8 vv = *(const bf16x8*)(kvbase + (size_t)nn * 98304 + 1280 + 64 * h + dq * 16);
#pragma unroll
    for (int j = 0; j < 8; ++j)
      *(bf16_t*)(lds + 20480 + (dq * 8 + j) * 528 + nn * 2) = vv[j];
  }

  // Q B-frags: q-window = wid*64 + qf*16 + c
  bf16x8 qa[4];
#pragma unroll
  for (int qf = 0; qf < 4; ++qf)
    qa[qf] = *(const bf16x8*)((const char*)QKV +
        (size_t)((b * 256 + wid * 64 + qf * 16 + c) * 64 + m) * 1536 + 256 + 64 * h + 16 * g);
  __syncthreads();

  f32x4 Ov[2][4];
  float mrun[4], lrun[4];
#pragma unroll
  for (int qf = 0; qf < 4; ++qf) {
    Ov[0][qf] = 0.f; Ov[1][qf] = 0.f;
    mrun[qf] = -3.0e38f; lrun[qf] = 0.f;
  }

  for (int kt = 0; kt < 4; ++kt) {
    bf16x8 kfr[4];
#pragma unroll
    for (int kf = 0; kf < 4; ++kf)
      kfr[kf] = *(const bf16x8*)(lds + (kt * 64 + kf * 16 + c) * 80 + 16 * g);
    bf16x8 vfr[2][2];
#pragma unroll
    for (int kb = 0; kb < 2; ++kb)
#pragma unroll
      for (int dt = 0; dt < 2; ++dt)
        vfr[kb][dt] = *(const bf16x8*)(lds + 20480 + (dt * 16 + c) * 528 + kt * 128 + kb * 64 + g * 16);

#pragma unroll
    for (int qf = 0; qf < 4; ++qf) {
      f32x4 S[4];
#pragma unroll
      for (int kf = 0; kf < 4; ++kf) {
        S[kf] = 0.f;
        S[kf] = __builtin_amdgcn_mfma_f32_16x16x32_bf16(kfr[kf], qa[qf], S[kf], 0, 0, 0);
      }
      // bias: pos2[h][q][key], key contiguous over r
      const float* pp = pos2 + ((h * 256 + wid * 64 + qf * 16 + c) * 256 + kt * 64 + 4 * g);
#pragma unroll
      for (int kf = 0; kf < 4; ++kf) {
        f32x4 pv = *(const f32x4*)(pp + kf * 16);
        S[kf] = S[kf] * SCALE_F + pv;
      }
      float tm0 = fmaxf(fmaxf(S[0][0], S[0][1]), fmaxf(S[0][2], S[0][3]));
      float tm1 = fmaxf(fmaxf(S[1][0], S[1][1]), fmaxf(S[1][2], S[1][3]));
      float tm2 = fmaxf(fmaxf(S[2][0], S[2][1]), fmaxf(S[2][2], S[2][3]));
      float tm3 = fmaxf(fmaxf(S[3][0], S[3][1]), fmaxf(S[3][2], S[3][3]));
      float t = fmaxf(fmaxf(tm0, tm1), fmaxf(tm2, tm3));
      t = fmaxf(t, __shfl_xor(t, 16));
      t = fmaxf(t, __shfl_xor(t, 32));
      float mo = mrun[qf];
      float mn = fmaxf(mo, t);
      float rsc = __expf(mo - mn);
      mrun[qf] = mn;
      float ls = 0.f;
#pragma unroll
      for (int kf = 0; kf < 4; ++kf)
#pragma unroll
        for (int r = 0; r < 4; ++r) {
          S[kf][r] = __expf(S[kf][r] - mn);
          ls += S[kf][r];
        }
      ls += __shfl_xor(ls, 16);
      ls += __shfl_xor(ls, 32);
      lrun[qf] = lrun[qf] * rsc + ls;
      Ov[0][qf] *= rsc;
      Ov[1][qf] *= rsc;
      // pack P into per-wave LDS [16q][64key], XOR-swizzled
#pragma unroll
      for (int kf = 0; kf < 4; ++kf)
#pragma unroll
        for (int p = 0; p < 2; ++p) {
          bf16x2 w;
          w[0] = (bf16_t)S[kf][2 * p];
          w[1] = (bf16_t)S[kf][2 * p + 1];
          int byteo = c * 128 + kf * 32 + g * 8 + p * 4;
          *(bf16x2*)(Pw + (byteo ^ ((c & 7) << 4))) = w;
        }
      bf16x8 pb0 = *(const bf16x8*)(Pw + ((c * 128 + g * 16) ^ ((c & 7) << 4)));
      bf16x8 pb1 = *(const bf16x8*)(Pw + ((c * 128 + 64 + g * 16) ^ ((c & 7) << 4)));
      Ov[0][qf] = __builtin_amdgcn_mfma_f32_16x16x32_bf16(vfr[0][0], pb0, Ov[0][qf], 0, 0, 0);
      Ov[1][qf] = __builtin_amdgcn_mfma_f32_16x16x32_bf16(vfr[0][1], pb0, Ov[1][qf], 0, 0, 0);
      Ov[0][qf] = __builtin_amdgcn_mfma_f32_16x16x32_bf16(vfr[1][0], pb1, Ov[0][qf], 0, 0, 0);
      Ov[1][qf] = __builtin_amdgcn_mfma_f32_16x16x32_bf16(vfr[1][1], pb1, Ov[1][qf], 0, 0, 0);
    }
  }

#pragma unroll
  for (int qf = 0; qf < 4; ++qf) {
    float inv = 1.0f / lrun[qf];
    int qrow = (b * 256 + wid * 64 + qf * 16 + c) * 64 + m;
#pragma unroll
    for (int dt = 0; dt < 2; ++dt) {
      bf16x4 ov;
      ov[0] = (bf16_t)(Ov[dt][qf][0] * inv); ov[1] = (bf16_t)(Ov[dt][qf][1] * inv);
      ov[2] = (bf16_t)(Ov[dt][qf][2] * inv); ov[3] = (bf16_t)(Ov[dt][qf][3] * inv);
      *(bf16x4*)(O + (size_t)qrow * 256 + 128 + 32 * h + dt * 16 + 4 * g) = ov;
    }
  }
}

// ---------------- GEMM3: out = attnO @ Wo + bo, unwindowed ----------------
__global__ __launch_bounds__(256) void gemm_out_k(
    const bf16_t* __restrict__ A, const bf16_t* __restrict__ Wt,
    const float* __restrict__ bo, float* __restrict__ out) {
  __shared__ bf16_t As[128 * 32];
  __shared__ bf16_t Bs[128 * 32];
  const int tid = threadIdx.x;
  const int row0 = blockIdx.x * 128;
  const int col0 = blockIdx.y * 128;
  const int lane = tid & 63, wv = tid >> 6;
  const int wm = (wv >> 1) * 64, wn = (wv & 1) * 64;
  const int tr = tid >> 2, kb = (tid & 3) * 8;

  const bf16_t* asrc0 = A + (size_t)(row0 + tr) * 256 + kb;
  const bf16_t* asrc1 = A + (size_t)(row0 + tr + 64) * 256 + kb;
  const bf16_t* bsrc0 = Wt + (col0 + tr) * 256 + kb;
  const bf16_t* bsrc1 = Wt + (col0 + tr + 64) * 256 + kb;

  f32x4 acc[4][4];
#pragma unroll
  for (int m = 0; m < 4; ++m)
#pragma unroll
    for (int n = 0; n < 4; ++n) acc[m][n] = 0.f;

  for (int ks = 0; ks < 256; ks += 32) {
    __syncthreads();
    *(int4*)&As[tr * 32 + kb] = *(const int4*)(asrc0 + ks);
    *(int4*)&As[(tr + 64) * 32 + kb] = *(const int4*)(asrc1 + ks);
    *(int4*)&Bs[tr * 32 + kb] = *(const int4*)(bsrc0 + ks);
    *(int4*)&Bs[(tr + 64) * 32 + kb] = *(const int4*)(bsrc1 + ks);
    __syncthreads();
    bf16x8 aF[4], bF[4];
#pragma unroll
    for (int m = 0; m < 4; ++m)
      aF[m] = *(const bf16x8*)&As[(wm + m * 16 + (lane & 15)) * 32 + (lane >> 4) * 8];
#pragma unroll
    for (int n = 0; n < 4; ++n)
      bF[n] = *(const bf16x8*)&Bs[(wn + n * 16 + (lane & 15)) * 32 + (lane >> 4) * 8];
#pragma unroll
    for (int m = 0; m < 4; ++m)
#pragma unroll
      for (int n = 0; n < 4; ++n)
        acc[m][n] = __builtin_amdgcn_mfma_f32_16x16x32_bf16(aF[m], bF[n], acc[m][n], 0, 0, 0);
  }

  float bias[4];
#pragma unroll
  for (int n = 0; n < 4; ++n) bias[n] = bo[col0 + wn + n * 16 + (lane & 15)];

#pragma unroll
  for (int m = 0; m < 4; ++m) {
#pragma unroll
    for (int r = 0; r < 4; ++r) {
      int grow = row0 + wm + m * 16 + ((lane >> 4) << 2) + r;
      int tok = token_of_row(grow);
      float* dst = out + (size_t)tok * 256 + col0 + wn + (lane & 15);
#pragma unroll
      for (int n = 0; n < 4; ++n) dst[n * 16] = acc[m][n][r] + bias[n];
    }
  }
}

extern "C" void kernel_launch(void* const* d_in, const int* in_sizes, int n_in,
                              void* d_out, int out_size, void* d_ws, size_t ws_size,
                              hipStream_t stream) {
  (void)in_sizes; (void)n_in; (void)out_size; (void)ws_size;
  const float* x    = (const float*)d_in[0];
  const float* Wq   = (const float*)d_in[1];
  const float* Wkv  = (const float*)d_in[2];
  const float* Wo   = (const float*)d_in[3];
  const float* bo   = (const float*)d_in[4];
  const float* pos1 = (const float*)d_in[5];
  const float* pos2 = (const float*)d_in[6];
  float* out = (float*)d_out;

  char* ws = (char*)d_ws;
  bf16_t* WqkvT = (bf16_t*)(ws);
  bf16_t* WoT   = (bf16_t*)(ws + 393216);
  bf16_t* QKVb  = (bf16_t*)(ws + 524288);
  bf16_t* attnO = (bf16_t*)(ws + 101187584ull);

  prep_k<<<1024, 256, 0, stream>>>(Wq, Wkv, Wo, WqkvT, WoT);
  dim3 g1(512, 6);
  gemm_qkv_k<<<g1, 256, 0, stream>>>(x, WqkvT, QKVb);
  attn1_k<<<1024, 256, 0, stream>>>(QKVb, pos1, attnO);
  attn2_k<<<1024, 256, 0, stream>>>(QKVb, pos2, attnO);
  dim3 g3(512, 2);
  gemm_out_k<<<g3, 256, 0, stream>>>(attnO, WoT, bo, out);
}

// Round 5
// 286.612 us; speedup vs baseline: 2.2677x; 1.0366x over previous
//
#include <hip/hip_runtime.h>
#include <hip/hip_bf16.h>
#include <stdint.h>

// HS-MSA: QKV proj (bf16 MFMA GEMM, single-fetch A-resident) -> swapped-operand
// MFMA flash attention -> out proj + bias.
//
// ws layout (bytes):
//   [0,        393216)   WqkvT bf16 [768][256]
//   [393216,   524288)   WoT   bf16 [256][256]
//   [524288,  101187584) QKV   bf16 [65536][768] windowed rows; Q:0-255 K:256-511 V:512-767
//   [101187584, 134742016) attnO bf16 [65536][256]

typedef float f32x4 __attribute__((ext_vector_type(4)));
typedef __bf16 bf16_t;
typedef __bf16 bf16x8 __attribute__((ext_vector_type(8)));
typedef __bf16 bf16x4 __attribute__((ext_vector_type(4)));
typedef __bf16 bf16x2 __attribute__((ext_vector_type(2)));

#define SCALE_F 0.17677669529663687f

__device__ __forceinline__ int token_of_row(int gr) {
  int b = gr >> 14, n = (gr >> 6) & 255, m = gr & 63;
  int h = ((n >> 4) << 3) + (m >> 3);
  int w = ((n & 15) << 3) + (m & 7);
  return ((b << 7) + h) * 128 + w;
}

// ---------------- prep: weight transpose + bf16 ----------------
__global__ __launch_bounds__(256) void prep_k(
    const float* __restrict__ Wq, const float* __restrict__ Wkv,
    const float* __restrict__ Wo, bf16_t* __restrict__ WqkvT,
    bf16_t* __restrict__ WoT) {
  int tid = blockIdx.x * 256 + threadIdx.x;
  if (tid < 196608) {
    int k = tid / 768, c = tid % 768;
    float v = (c < 256) ? Wq[k * 256 + c] : Wkv[k * 512 + (c - 256)];
    WqkvT[c * 256 + k] = (bf16_t)v;
  } else if (tid < 262144) {
    int t = tid - 196608;
    int k = t >> 8, c = t & 255;
    WoT[c * 256 + k] = (bf16_t)Wo[k * 256 + c];
  }
}

// ---------------- GEMM1: QKV(bf16) = x @ [Wq|Wk|Wv], A-resident ----------------
// grid = 512 row-blocks; x fetched ONCE; 6 col-tiles x 4 K-chunks inside.
// LDS: A [128 rows][512B] swizzled @0 (64KB) ; B chunk [128 cols][128B] swizzled @65536 (16KB)
__global__ __launch_bounds__(256, 2) void gemm_qkv_k(
    const float* __restrict__ x, const bf16_t* __restrict__ Wt,
    bf16_t* __restrict__ QKV) {
  __shared__ char lds[81920];
  char* Bs = lds + 65536;
  const int tid = threadIdx.x;
  const int row0 = blockIdx.x * 128;
  const int lane = tid & 63, wv = tid >> 6;
  const int wm = (wv >> 1) * 64, wn = (wv & 1) * 64;
  const int g = lane >> 4, c = lane & 15;

  // ---- stage A once: fp32 -> bf16, swizzled ----
#pragma unroll
  for (int it = 0; it < 16; ++it) {
    int u = it * 256 + tid;            // 8-float group index, 4096 total
    int row = u >> 5;
    int kf4 = (u & 31) * 8;            // float offset within row
    const float* src = x + (size_t)token_of_row(row0 + row) * 256 + kf4;
    f32x4 a0 = *(const f32x4*)src;
    f32x4 a1 = *(const f32x4*)(src + 4);
    bf16x8 o;
    o[0]=(bf16_t)a0[0]; o[1]=(bf16_t)a0[1]; o[2]=(bf16_t)a0[2]; o[3]=(bf16_t)a0[3];
    o[4]=(bf16_t)a1[0]; o[5]=(bf16_t)a1[1]; o[6]=(bf16_t)a1[2]; o[7]=(bf16_t)a1[3];
    int bo = (u & 31) * 16;            // byte offset within row
    *(bf16x8*)(lds + row * 512 + (bo ^ ((row & 7) << 4))) = o;
  }
  __syncthreads();

  for (int nc = 0; nc < 6; ++nc) {
    f32x4 acc[4][4];
#pragma unroll
    for (int m = 0; m < 4; ++m)
#pragma unroll
      for (int n = 0; n < 4; ++n) acc[m][n] = 0.f;

    for (int kc = 0; kc < 4; ++kc) {
      // stage B chunk: cols nc*128..+128, k = kc*64..+64 (L2-hot weights)
#pragma unroll
      for (int j = 0; j < 4; ++j) {
        int unit = tid * 4 + j;        // 16B unit: 1024 total
        int col = unit >> 3, kp = unit & 7;
        int4 w = *(const int4*)((const char*)Wt +
            (size_t)(nc * 128 + col) * 512 + kc * 128 + kp * 16);
        *(int4*)(Bs + col * 128 + ((kp * 16) ^ ((col & 7) << 4))) = w;
      }
      __syncthreads();

#pragma unroll
      for (int kf = 0; kf < 2; ++kf) {
        bf16x8 aF[4], bF[4];
        int kbyteA = kc * 128 + kf * 64 + g * 16;
        int kbyteB = kf * 64 + g * 16;
#pragma unroll
        for (int m = 0; m < 4; ++m) {
          int row = wm + m * 16 + c;
          aF[m] = *(const bf16x8*)(lds + row * 512 + (kbyteA ^ ((row & 7) << 4)));
        }
#pragma unroll
        for (int n = 0; n < 4; ++n) {
          int col = wn + n * 16 + c;
          bF[n] = *(const bf16x8*)(Bs + col * 128 + (kbyteB ^ ((col & 7) << 4)));
        }
#pragma unroll
        for (int m = 0; m < 4; ++m)
#pragma unroll
          for (int n = 0; n < 4; ++n)
            acc[m][n] = __builtin_amdgcn_mfma_f32_16x16x32_bf16(aF[m], bF[n], acc[m][n], 0, 0, 0);
      }
      __syncthreads();
    }

    // C/D layout (verified): col = lane&15, row = (lane>>4)*4 + r
#pragma unroll
    for (int m = 0; m < 4; ++m) {
#pragma unroll
      for (int r = 0; r < 4; ++r) {
        int grow = row0 + wm + m * 16 + (g << 2) + r;
        bf16_t* dst = QKV + (size_t)grow * 768 + nc * 128 + wn + c;
#pragma unroll
        for (int n = 0; n < 4; ++n) dst[n * 16] = (bf16_t)acc[m][n][r];
      }
    }
  }
}

// ---------------- attn1: block=(b,n), wave=head; S^T=K*Q^T, O^T=V^T*P^T ----------------
// LDS: K [4h][64key][80B] @0 ; Vt [4h][32d][144B] @20480 ; P per-wave 2KB @38912
__global__ __launch_bounds__(256, 3) void attn1_k(
    const bf16_t* __restrict__ QKV, const float* __restrict__ pos1,
    bf16_t* __restrict__ O) {
  __shared__ char lds[47104];
  const int bid = blockIdx.x;
  const int n = bid & 255, b = bid >> 8;
  const int tid = threadIdx.x;
  const int lane = tid & 63, h = tid >> 6;
  const int g = lane >> 4, c = lane & 15;
  char* Pw = lds + 38912 + h * 2048;
  const size_t rowbase = (size_t)(b * 256 + n) * 64;
  const char* base = (const char*)QKV + rowbase * 1536;

  // stage K (head-sliced rows, 64B each)
#pragma unroll
  for (int it = 0; it < 4; ++it) {
    int idx = it * 256 + tid;
    int hh = idx >> 8, key = (idx >> 2) & 63, ch4 = idx & 3;
    int4 kk = *(const int4*)(base + (size_t)key * 1536 + 512 + 64 * hh + ch4 * 16);
    *(int4*)(lds + (hh * 64 + key) * 80 + ch4 * 16) = kk;
  }
  // stage V transposed: Vt[h][d][m]
#pragma unroll
  for (int it = 0; it < 4; ++it) {
    int idx = it * 256 + tid;
    int hh = idx >> 8, mm = (idx >> 2) & 63, dq = idx & 3;
    bf16x8 vv = *(const bf16x8*)(base + (size_t)mm * 1536 + 1024 + 64 * hh + dq * 16);
#pragma unroll
    for (int j = 0; j < 8; ++j)
      *(bf16_t*)(lds + 20480 + hh * 4608 + (dq * 8 + j) * 144 + mm * 2) = vv[j];
  }

  // Q B-frags: q = lane&15
  bf16x8 qa[4];
#pragma unroll
  for (int qf = 0; qf < 4; ++qf)
    qa[qf] = *(const bf16x8*)(base + (size_t)(qf * 16 + c) * 1536 + 64 * h + 16 * g);
  __syncthreads();

  // K A-frags + V^T A-frags
  bf16x8 kfr[4];
#pragma unroll
  for (int kf = 0; kf < 4; ++kf)
    kfr[kf] = *(const bf16x8*)(lds + (h * 64 + kf * 16 + c) * 80 + 16 * g);
  bf16x8 vfr[2][2];
#pragma unroll
  for (int kb = 0; kb < 2; ++kb)
#pragma unroll
    for (int dt = 0; dt < 2; ++dt)
      vfr[kb][dt] = *(const bf16x8*)(lds + 20480 + h * 4608 + (dt * 16 + c) * 144 + kb * 64 + g * 16);

  f32x4 Ov[2][4];
#pragma unroll
  for (int dt = 0; dt < 2; ++dt)
#pragma unroll
    for (int qf = 0; qf < 4; ++qf) Ov[dt][qf] = 0.f;

#pragma unroll
  for (int qf = 0; qf < 4; ++qf) {
    f32x4 S[4];
#pragma unroll
    for (int kf = 0; kf < 4; ++kf) {
      S[kf] = 0.f;
      S[kf] = __builtin_amdgcn_mfma_f32_16x16x32_bf16(kfr[kf], qa[qf], S[kf], 0, 0, 0);
    }
    // bias: pos1[h][q][key], key contiguous over r
    const float* pp = pos1 + ((h * 64 + qf * 16 + c) * 64 + 4 * g);
#pragma unroll
    for (int kf = 0; kf < 4; ++kf) {
      f32x4 pv = *(const f32x4*)(pp + kf * 16);
      S[kf] = S[kf] * SCALE_F + pv;
    }
    float tm0 = fmaxf(fmaxf(S[0][0], S[0][1]), fmaxf(S[0][2], S[0][3]));
    float tm1 = fmaxf(fmaxf(S[1][0], S[1][1]), fmaxf(S[1][2], S[1][3]));
    float tm2 = fmaxf(fmaxf(S[2][0], S[2][1]), fmaxf(S[2][2], S[2][3]));
    float tm3 = fmaxf(fmaxf(S[3][0], S[3][1]), fmaxf(S[3][2], S[3][3]));
    float t = fmaxf(fmaxf(tm0, tm1), fmaxf(tm2, tm3));
    t = fmaxf(t, __shfl_xor(t, 16));
    t = fmaxf(t, __shfl_xor(t, 32));
    float ls = 0.f;
#pragma unroll
    for (int kf = 0; kf < 4; ++kf)
#pragma unroll
      for (int r = 0; r < 4; ++r) {
        S[kf][r] = __expf(S[kf][r] - t);
        ls += S[kf][r];
      }
    ls += __shfl_xor(ls, 16);
    ls += __shfl_xor(ls, 32);
    float inv = 1.0f / ls;
    // pack normalized P into per-wave LDS [16q][64key], XOR-swizzled
#pragma unroll
    for (int kf = 0; kf < 4; ++kf)
#pragma unroll
      for (int p = 0; p < 2; ++p) {
        bf16x2 w;
        w[0] = (bf16_t)(S[kf][2 * p] * inv);
        w[1] = (bf16_t)(S[kf][2 * p + 1] * inv);
        int byteo = c * 128 + kf * 32 + g * 8 + p * 4;
        *(bf16x2*)(Pw + (byteo ^ ((c & 7) << 4))) = w;
      }
    bf16x8 pb0 = *(const bf16x8*)(Pw + ((c * 128 + g * 16) ^ ((c & 7) << 4)));
    bf16x8 pb1 = *(const bf16x8*)(Pw + ((c * 128 + 64 + g * 16) ^ ((c & 7) << 4)));
    Ov[0][qf] = __builtin_amdgcn_mfma_f32_16x16x32_bf16(vfr[0][0], pb0, Ov[0][qf], 0, 0, 0);
    Ov[1][qf] = __builtin_amdgcn_mfma_f32_16x16x32_bf16(vfr[0][1], pb0, Ov[1][qf], 0, 0, 0);
    Ov[0][qf] = __builtin_amdgcn_mfma_f32_16x16x32_bf16(vfr[1][0], pb1, Ov[0][qf], 0, 0, 0);
    Ov[1][qf] = __builtin_amdgcn_mfma_f32_16x16x32_bf16(vfr[1][1], pb1, Ov[1][qf], 0, 0, 0);
  }

  // store: lane holds O^T[d = dt*16+4g+r][q = qf*16+c]
#pragma unroll
  for (int qf = 0; qf < 4; ++qf)
#pragma unroll
    for (int dt = 0; dt < 2; ++dt) {
      int row = (b * 256 + n) * 64 + qf * 16 + c;
      bf16x4 ov;
      ov[0] = (bf16_t)Ov[dt][qf][0]; ov[1] = (bf16_t)Ov[dt][qf][1];
      ov[2] = (bf16_t)Ov[dt][qf][2]; ov[3] = (bf16_t)Ov[dt][qf][3];
      *(bf16x4*)(O + (size_t)row * 256 + 32 * h + dt * 16 + 4 * g) = ov;
    }
}

// ---------------- attn2: block=(b,m,h), wave=qtile; flash over 4 key tiles ----------------
// LDS: K [256key][80B] @0 ; Vt [32d][528B] @20480 ; P per-wave 2KB @37376
__global__ __launch_bounds__(256, 3) void attn2_k(
    const bf16_t* __restrict__ QKV, const float* __restrict__ pos2,
    bf16_t* __restrict__ O) {
  __shared__ char lds[45568];
  const int bid = blockIdx.x;
  const int h = bid & 3, m = (bid >> 2) & 63, b = bid >> 8;
  const int tid = threadIdx.x;
  const int lane = tid & 63, wid = tid >> 6;
  const int g = lane >> 4, c = lane & 15;
  char* Pw = lds + 37376 + wid * 2048;
  const char* kvbase = (const char*)QKV + (size_t)(b * 16384 + m) * 1536;

  // stage K (keys = windows, head slice 64B each)
#pragma unroll
  for (int it = 0; it < 4; ++it) {
    int idx = it * 256 + tid;
    int key = idx >> 2, ch4 = idx & 3;
    int4 kk = *(const int4*)(kvbase + (size_t)key * 98304 + 768 + 64 * h + ch4 * 16);
    *(int4*)(lds + key * 80 + ch4 * 16) = kk;
  }
  // stage V transposed: Vt[d][key]
#pragma unroll
  for (int it = 0; it < 4; ++it) {
    int idx = it * 256 + tid;
    int nn = idx >> 2, dq = idx & 3;
    bf16x8 vv = *(const bf16x8*)(kvbase + (size_t)nn * 98304 + 1280 + 64 * h + dq * 16);
#pragma unroll
    for (int j = 0; j < 8; ++j)
      *(bf16_t*)(lds + 20480 + (dq * 8 + j) * 528 + nn * 2) = vv[j];
  }

  // Q B-frags: q-window = wid*64 + qf*16 + c
  bf16x8 qa[4];
#pragma unroll
  for (int qf = 0; qf < 4; ++qf)
    qa[qf] = *(const bf16x8*)((const char*)QKV +
        (size_t)((b * 256 + wid * 64 + qf * 16 + c) * 64 + m) * 1536 + 256 + 64 * h + 16 * g);
  __syncthreads();

  f32x4 Ov[2][4];
  float mrun[4], lrun[4];
#pragma unroll
  for (int qf = 0; qf < 4; ++qf) {
    Ov[0][qf] = 0.f; Ov[1][qf] = 0.f;
    mrun[qf] = -3.0e38f; lrun[qf] = 0.f;
  }

  for (int kt = 0; kt < 4; ++kt) {
    bf16x8 kfr[4];
#pragma unroll
    for (int kf = 0; kf < 4; ++kf)
      kfr[kf] = *(const bf16x8*)(lds + (kt * 64 + kf * 16 + c) * 80 + 16 * g);
    bf16x8 vfr[2][2];
#pragma unroll
    for (int kb = 0; kb < 2; ++kb)
#pragma unroll
      for (int dt = 0; dt < 2; ++dt)
        vfr[kb][dt] = *(const bf16x8*)(lds + 20480 + (dt * 16 + c) * 528 + kt * 128 + kb * 64 + g * 16);

#pragma unroll
    for (int qf = 0; qf < 4; ++qf) {
      f32x4 S[4];
#pragma unroll
      for (int kf = 0; kf < 4; ++kf) {
        S[kf] = 0.f;
        S[kf] = __builtin_amdgcn_mfma_f32_16x16x32_bf16(kfr[kf], qa[qf], S[kf], 0, 0, 0);
      }
      // bias: pos2[h][q][key], key contiguous over r
      const float* pp = pos2 + ((h * 256 + wid * 64 + qf * 16 + c) * 256 + kt * 64 + 4 * g);
#pragma unroll
      for (int kf = 0; kf < 4; ++kf) {
        f32x4 pv = *(const f32x4*)(pp + kf * 16);
        S[kf] = S[kf] * SCALE_F + pv;
      }
      float tm0 = fmaxf(fmaxf(S[0][0], S[0][1]), fmaxf(S[0][2], S[0][3]));
      float tm1 = fmaxf(fmaxf(S[1][0], S[1][1]), fmaxf(S[1][2], S[1][3]));
      float tm2 = fmaxf(fmaxf(S[2][0], S[2][1]), fmaxf(S[2][2], S[2][3]));
      float tm3 = fmaxf(fmaxf(S[3][0], S[3][1]), fmaxf(S[3][2], S[3][3]));
      float t = fmaxf(fmaxf(tm0, tm1), fmaxf(tm2, tm3));
      t = fmaxf(t, __shfl_xor(t, 16));
      t = fmaxf(t, __shfl_xor(t, 32));
      float mo = mrun[qf];
      float mn = fmaxf(mo, t);
      float rsc = __expf(mo - mn);
      mrun[qf] = mn;
      float ls = 0.f;
#pragma unroll
      for (int kf = 0; kf < 4; ++kf)
#pragma unroll
        for (int r = 0; r < 4; ++r) {
          S[kf][r] = __expf(S[kf][r] - mn);
          ls += S[kf][r];
        }
      ls += __shfl_xor(ls, 16);
      ls += __shfl_xor(ls, 32);
      lrun[qf] = lrun[qf] * rsc + ls;
      Ov[0][qf] *= rsc;
      Ov[1][qf] *= rsc;
      // pack P into per-wave LDS [16q][64key], XOR-swizzled
#pragma unroll
      for (int kf = 0; kf < 4; ++kf)
#pragma unroll
        for (int p = 0; p < 2; ++p) {
          bf16x2 w;
          w[0] = (bf16_t)S[kf][2 * p];
          w[1] = (bf16_t)S[kf][2 * p + 1];
          int byteo = c * 128 + kf * 32 + g * 8 + p * 4;
          *(bf16x2*)(Pw + (byteo ^ ((c & 7) << 4))) = w;
        }
      bf16x8 pb0 = *(const bf16x8*)(Pw + ((c * 128 + g * 16) ^ ((c & 7) << 4)));
      bf16x8 pb1 = *(const bf16x8*)(Pw + ((c * 128 + 64 + g * 16) ^ ((c & 7) << 4)));
      Ov[0][qf] = __builtin_amdgcn_mfma_f32_16x16x32_bf16(vfr[0][0], pb0, Ov[0][qf], 0, 0, 0);
      Ov[1][qf] = __builtin_amdgcn_mfma_f32_16x16x32_bf16(vfr[0][1], pb0, Ov[1][qf], 0, 0, 0);
      Ov[0][qf] = __builtin_amdgcn_mfma_f32_16x16x32_bf16(vfr[1][0], pb1, Ov[0][qf], 0, 0, 0);
      Ov[1][qf] = __builtin_amdgcn_mfma_f32_16x16x32_bf16(vfr[1][1], pb1, Ov[1][qf], 0, 0, 0);
    }
  }

#pragma unroll
  for (int qf = 0; qf < 4; ++qf) {
    float inv = 1.0f / lrun[qf];
    int qrow = (b * 256 + wid * 64 + qf * 16 + c) * 64 + m;
#pragma unroll
    for (int dt = 0; dt < 2; ++dt) {
      bf16x4 ov;
      ov[0] = (bf16_t)(Ov[dt][qf][0] * inv); ov[1] = (bf16_t)(Ov[dt][qf][1] * inv);
      ov[2] = (bf16_t)(Ov[dt][qf][2] * inv); ov[3] = (bf16_t)(Ov[dt][qf][3] * inv);
      *(bf16x4*)(O + (size_t)qrow * 256 + 128 + 32 * h + dt * 16 + 4 * g) = ov;
    }
  }
}

// ---------------- GEMM3: out = attnO @ Wo + bo, unwindowed ----------------
__global__ __launch_bounds__(256) void gemm_out_k(
    const bf16_t* __restrict__ A, const bf16_t* __restrict__ Wt,
    const float* __restrict__ bo, float* __restrict__ out) {
  __shared__ bf16_t As[128 * 32];
  __shared__ bf16_t Bs[128 * 32];
  const int tid = threadIdx.x;
  const int row0 = blockIdx.x * 128;
  const int col0 = blockIdx.y * 128;
  const int lane = tid & 63, wv = tid >> 6;
  const int wm = (wv >> 1) * 64, wn = (wv & 1) * 64;
  const int tr = tid >> 2, kb = (tid & 3) * 8;

  const bf16_t* asrc0 = A + (size_t)(row0 + tr) * 256 + kb;
  const bf16_t* asrc1 = A + (size_t)(row0 + tr + 64) * 256 + kb;
  const bf16_t* bsrc0 = Wt + (col0 + tr) * 256 + kb;
  const bf16_t* bsrc1 = Wt + (col0 + tr + 64) * 256 + kb;

  f32x4 acc[4][4];
#pragma unroll
  for (int m = 0; m < 4; ++m)
#pragma unroll
    for (int n = 0; n < 4; ++n) acc[m][n] = 0.f;

  for (int ks = 0; ks < 256; ks += 32) {
    __syncthreads();
    *(int4*)&As[tr * 32 + kb] = *(const int4*)(asrc0 + ks);
    *(int4*)&As[(tr + 64) * 32 + kb] = *(const int4*)(asrc1 + ks);
    *(int4*)&Bs[tr * 32 + kb] = *(const int4*)(bsrc0 + ks);
    *(int4*)&Bs[(tr + 64) * 32 + kb] = *(const int4*)(bsrc1 + ks);
    __syncthreads();
    bf16x8 aF[4], bF[4];
#pragma unroll
    for (int m = 0; m < 4; ++m)
      aF[m] = *(const bf16x8*)&As[(wm + m * 16 + (lane & 15)) * 32 + (lane >> 4) * 8];
#pragma unroll
    for (int n = 0; n < 4; ++n)
      bF[n] = *(const bf16x8*)&Bs[(wn + n * 16 + (lane & 15)) * 32 + (lane >> 4) * 8];
#pragma unroll
    for (int m = 0; m < 4; ++m)
#pragma unroll
      for (int n = 0; n < 4; ++n)
        acc[m][n] = __builtin_amdgcn_mfma_f32_16x16x32_bf16(aF[m], bF[n], acc[m][n], 0, 0, 0);
  }

  float bias[4];
#pragma unroll
  for (int n = 0; n < 4; ++n) bias[n] = bo[col0 + wn + n * 16 + (lane & 15)];

#pragma unroll
  for (int m = 0; m < 4; ++m) {
#pragma unroll
    for (int r = 0; r < 4; ++r) {
      int grow = row0 + wm + m * 16 + ((lane >> 4) << 2) + r;
      int tok = token_of_row(grow);
      float* dst = out + (size_t)tok * 256 + col0 + wn + (lane & 15);
#pragma unroll
      for (int n = 0; n < 4; ++n) dst[n * 16] = acc[m][n][r] + bias[n];
    }
  }
}

extern "C" void kernel_launch(void* const* d_in, const int* in_sizes, int n_in,
                              void* d_out, int out_size, void* d_ws, size_t ws_size,
                              hipStream_t stream) {
  (void)in_sizes; (void)n_in; (void)out_size; (void)ws_size;
  const float* x    = (const float*)d_in[0];
  const float* Wq   = (const float*)d_in[1];
  const float* Wkv  = (const float*)d_in[2];
  const float* Wo   = (const float*)d_in[3];
  const float* bo   = (const float*)d_in[4];
  const float* pos1 = (const float*)d_in[5];
  const float* pos2 = (const float*)d_in[6];
  float* out = (float*)d_out;

  char* ws = (char*)d_ws;
  bf16_t* WqkvT = (bf16_t*)(ws);
  bf16_t* WoT   = (bf16_t*)(ws + 393216);
  bf16_t* QKVb  = (bf16_t*)(ws + 524288);
  bf16_t* attnO = (bf16_t*)(ws + 101187584ull);

  prep_k<<<1024, 256, 0, stream>>>(Wq, Wkv, Wo, WqkvT, WoT);
  gemm_qkv_k<<<512, 256, 0, stream>>>(x, WqkvT, QKVb);
  attn1_k<<<1024, 256, 0, stream>>>(QKVb, pos1, attnO);
  attn2_k<<<1024, 256, 0, stream>>>(QKVb, pos2, attnO);
  dim3 g3(512, 2);
  gemm_out_k<<<g3, 256, 0, stream>>>(attnO, WoT, bo, out);
}